// Round 1
// baseline (249.662 us; speedup 1.0000x reference)
//
#include <hip/hip_runtime.h>

#define CIN  3
#define COUT 32
// spatial tile per block: 4 (z) x 8 (y) x 8 (x)  -> 4 pool outputs (1x2x2)
#define IZ 6
#define IY 10
#define IX 10
#define XT_N (CIN*IZ*IY*IX)   // 1800

__global__ __launch_bounds__(256, 4)
void conv_sm_pool_kernel(const float* __restrict__ x,
                         const float* __restrict__ w,
                         const float* __restrict__ b,
                         float* __restrict__ out)
{
    __shared__ __align__(16) float xs[XT_N];        // input halo tile
    __shared__ __align__(16) float ws[81 * COUT];   // wT[k][c]
    __shared__ float bs[COUT];

    const int tid = threadIdx.x;
    const int nbz = blockIdx.x;      // n*16 + bz
    const int n   = nbz >> 4;
    const int bz  = nbz & 15;        // od (pool-z output index), spatial z0 = 4*bz
    const int by  = blockIdx.y;      // spatial y0 = 8*by
    const int bx  = blockIdx.z;      // spatial x0 = 8*bx

    // ---- stage transposed weights: ws[k*32 + c] = w[c*81 + k] ----
    for (int i = tid; i < 81 * COUT; i += 256) {
        int k = i >> 5;
        int c = i & 31;
        ws[i] = w[c * 81 + k];
    }
    if (tid < COUT) bs[tid] = b[tid];

    // ---- stage input tile (zero-padded halo) ----
    const int z0 = bz * 4 - 1;
    const int y0 = by * 8 - 1;
    const int x0 = bx * 8 - 1;
    for (int i = tid; i < XT_N; i += 256) {
        int t  = i;
        int xx = t % IX; t /= IX;
        int yy = t % IY; t /= IY;
        int zz = t % IZ; t /= IZ;
        int ci = t;
        int gz = z0 + zz, gy = y0 + yy, gx = x0 + xx;
        float v = 0.0f;
        if ((unsigned)gz < 64u && (unsigned)gy < 64u && (unsigned)gx < 64u)
            v = x[(((size_t)(n * CIN + ci) << 6 | gz) << 12) + (gy << 6) + gx];
        xs[i] = v;
    }
    __syncthreads();

    // ---- per-lane spatial point ----
    const int lane = tid & 63;
    const int wv   = tid >> 6;            // wave id 0..3 -> which pool output
    const int dz   = lane >> 4;           // 0..3
    const int dy   = (lane >> 2) & 3;     // 0..3
    const int dx   = lane & 3;            // 0..3
    const int py   = 4 * (wv >> 1) + dy;  // 0..7 within tile
    const int px   = 4 * (wv & 1) + dx;   // 0..7

    float acc[COUT];
    #pragma unroll
    for (int c = 0; c < COUT; ++c) acc[c] = bs[c];

    // ---- conv: 81 taps x 32 channels ----
    #pragma unroll 1
    for (int ci = 0; ci < CIN; ++ci) {
        #pragma unroll 1
        for (int kd = 0; kd < 3; ++kd) {
            const float* xrow = &xs[ci * (IZ*IY*IX) + (dz + kd) * (IY*IX)];
            #pragma unroll
            for (int kh = 0; kh < 3; ++kh) {
                #pragma unroll
                for (int kw = 0; kw < 3; ++kw) {
                    float xv = xrow[(py + kh) * IX + (px + kw)];
                    const int k = ((ci * 3 + kd) * 3 + kh) * 3 + kw;
                    const float4* wp = (const float4*)&ws[k * COUT];
                    #pragma unroll
                    for (int c4 = 0; c4 < 8; ++c4) {
                        float4 wf = wp[c4];
                        acc[4*c4 + 0] += xv * wf.x;
                        acc[4*c4 + 1] += xv * wf.y;
                        acc[4*c4 + 2] += xv * wf.z;
                        acc[4*c4 + 3] += xv * wf.w;
                    }
                }
            }
        }
    }

    // ---- softmax over channels (in-register) ----
    float m = acc[0];
    #pragma unroll
    for (int c = 1; c < COUT; ++c) m = fmaxf(m, acc[c]);
    float s = 0.0f;
    #pragma unroll
    for (int c = 0; c < COUT; ++c) { acc[c] = __expf(acc[c] - m); s += acc[c]; }
    const float rs = 1.0f / s;
    #pragma unroll
    for (int c = 0; c < COUT; ++c) acc[c] *= rs;

    // ---- 4x4x4 max-pool = full-wave butterfly max per channel ----
    #pragma unroll
    for (int c = 0; c < COUT; ++c) {
        float v = acc[c];
        v = fmaxf(v, __shfl_xor(v, 1));
        v = fmaxf(v, __shfl_xor(v, 2));
        v = fmaxf(v, __shfl_xor(v, 4));
        v = fmaxf(v, __shfl_xor(v, 8));
        v = fmaxf(v, __shfl_xor(v, 16));
        v = fmaxf(v, __shfl_xor(v, 32));
        acc[c] = v;
    }

    // ---- lane 0 of each wave writes its pool output for all 32 channels ----
    if (lane == 0) {
        const int od = bz;
        const int oh = 2 * by + (wv >> 1);
        const int ow = 2 * bx + (wv & 1);
        size_t base = (((size_t)n * COUT) << 12) + ((size_t)od << 8) + (oh << 4) + ow;
        #pragma unroll
        for (int c = 0; c < COUT; ++c)
            out[base + ((size_t)c << 12)] = acc[c];
    }
}

extern "C" void kernel_launch(void* const* d_in, const int* in_sizes, int n_in,
                              void* d_out, int out_size, void* d_ws, size_t ws_size,
                              hipStream_t stream) {
    const float* x  = (const float*)d_in[0];
    const float* w  = (const float*)d_in[1];
    const float* b  = (const float*)d_in[2];
    float* out = (float*)d_out;

    dim3 grid(8 * 16, 8, 8);   // (n*od, by, bx)
    dim3 block(256);
    conv_sm_pool_kernel<<<grid, block, 0, stream>>>(x, w, b, out);
}

// Round 2
// 169.836 us; speedup vs baseline: 1.4700x; 1.4700x over previous
//
#include <hip/hip_runtime.h>

#define CIN  3
#define COUT 32
// block spatial tile: 4 (z) x 16 (y) x 16 (x); each lane owns a 4-deep z-column
#define IZ 6
#define IY 18
#define IX 18
#define XT_N (CIN*IZ*IY*IX)   // 5832

__global__ __launch_bounds__(256, 2)
void conv_sm_pool_kernel(const float* __restrict__ x,
                         const float* __restrict__ w,
                         const float* __restrict__ b,
                         float* __restrict__ out)
{
    __shared__ __align__(16) float xs[XT_N];        // input halo tile
    __shared__ __align__(16) float ws[81 * COUT];   // wT[k][c]
    __shared__ float bs[COUT];

    const int tid = threadIdx.x;
    const int nbz = blockIdx.x;      // n*16 + bz
    const int n   = nbz >> 4;
    const int bz  = nbz & 15;        // z0 = 4*bz  (also od)
    const int by  = blockIdx.y;      // y0 = 16*by
    const int bx  = blockIdx.z;      // x0 = 16*bx

    // ---- stage transposed weights: ws[k*32 + c] = w[c*81 + k] ----
    for (int i = tid; i < 81 * COUT; i += 256) {
        int k = i >> 5;
        int c = i & 31;
        ws[i] = w[c * 81 + k];
    }
    if (tid < COUT) bs[tid] = b[tid];

    // ---- stage input halo tile (zero-padded) ----
    const int z0 = bz * 4 - 1;
    const int y0 = by * 16 - 1;
    const int x0 = bx * 16 - 1;
    for (int i = tid; i < XT_N; i += 256) {
        int t  = i;
        int xx = t % IX; t /= IX;
        int yy = t % IY; t /= IY;
        int zz = t % IZ; t /= IZ;
        int ci = t;
        int gz = z0 + zz, gy = y0 + yy, gx = x0 + xx;
        float v = 0.0f;
        if ((unsigned)gz < 64u && (unsigned)gy < 64u && (unsigned)gx < 64u)
            v = x[(((size_t)(n * CIN + ci) << 6 | gz) << 12) + (gy << 6) + gx];
        xs[i] = v;
    }
    __syncthreads();

    // ---- lane -> (py, px); each lane computes z = 4*bz + 0..3 ----
    const int lane = tid & 63;
    const int wv   = tid >> 6;            // wave 0..3 -> 8x8 (y,x) quadrant of tile
    const int q    = lane >> 4;           // 0..3 -> 4x4 sub-quadrant (one pool output)
    const int r    = lane & 15;
    const int ry   = r >> 2;
    const int rx   = r & 3;
    const int py   = ((wv >> 1) << 3) + ((q >> 1) << 2) + ry;   // 0..15
    const int px   = ((wv & 1) << 3) + ((q & 1) << 2) + rx;     // 0..15

    float acc[4][COUT];
    #pragma unroll
    for (int p = 0; p < 4; ++p)
        #pragma unroll
        for (int c = 0; c < COUT; ++c) acc[p][c] = 0.0f;

    // ---- conv: per (ci,kh): load 6x3 x-window, do 1152 FMAs ----
    #pragma unroll 1
    for (int ci = 0; ci < CIN; ++ci) {
        #pragma unroll 1
        for (int kh = 0; kh < 3; ++kh) {
            const int xb = ci * (IZ*IY*IX) + (py + kh) * IX + px;
            float xr[IZ][3];
            #pragma unroll
            for (int zz = 0; zz < IZ; ++zz)
                #pragma unroll
                for (int j = 0; j < 3; ++j)
                    xr[zz][j] = xs[xb + zz * (IY*IX) + j];

            #pragma unroll
            for (int kw = 0; kw < 3; ++kw) {
                #pragma unroll
                for (int kd = 0; kd < 3; ++kd) {
                    const int k = ((ci * 3 + kd) * 3 + kh) * 3 + kw;
                    const float4* wp = (const float4*)&ws[k * COUT];
                    #pragma unroll
                    for (int c4 = 0; c4 < 8; ++c4) {
                        const float4 wf = wp[c4];
                        #pragma unroll
                        for (int p = 0; p < 4; ++p) {
                            const float xv = xr[p + kd][kw];
                            acc[p][4*c4 + 0] += xv * wf.x;
                            acc[p][4*c4 + 1] += xv * wf.y;
                            acc[p][4*c4 + 2] += xv * wf.z;
                            acc[p][4*c4 + 3] += xv * wf.w;
                        }
                    }
                }
            }
        }
    }

    // ---- bias + softmax per point, then z-max in-lane ----
    float res[COUT];
    #pragma unroll
    for (int p = 0; p < 4; ++p) {
        float m = acc[p][0] + bs[0];
        #pragma unroll
        for (int c = 1; c < COUT; ++c) {
            acc[p][c] += bs[c];
            m = fmaxf(m, acc[p][c]);
        }
        acc[p][0] += 0.0f;  // acc[p][0] already has no bias added; fix below
        float s = 0.0f;
        #pragma unroll
        for (int c = 0; c < COUT; ++c) {
            float t = (c == 0) ? (acc[p][0] + bs[0]) : acc[p][c];
            t = __expf(t - m);
            acc[p][c] = t;
            s += t;
        }
        const float rs = 1.0f / s;
        #pragma unroll
        for (int c = 0; c < COUT; ++c) {
            float v = acc[p][c] * rs;
            if (p == 0) res[c] = v; else res[c] = fmaxf(res[c], v);
        }
    }

    // ---- (y,x) 4x4 pool: butterfly max over 16-lane group ----
    #pragma unroll
    for (int c = 0; c < COUT; ++c) {
        float v = res[c];
        v = fmaxf(v, __shfl_xor(v, 1));
        v = fmaxf(v, __shfl_xor(v, 2));
        v = fmaxf(v, __shfl_xor(v, 4));
        v = fmaxf(v, __shfl_xor(v, 8));
        res[c] = v;
    }

    // ---- lane r==0 of each 16-lane group writes 32 channels ----
    if (r == 0) {
        const int od = bz;
        const int oh = 4 * by + 2 * (wv >> 1) + (q >> 1);
        const int ow = 4 * bx + 2 * (wv & 1) + (q & 1);
        size_t base = (((size_t)n * COUT) << 12) + ((size_t)od << 8) + (oh << 4) + ow;
        #pragma unroll
        for (int c = 0; c < COUT; ++c)
            out[base + ((size_t)c << 12)] = res[c];
    }
}

extern "C" void kernel_launch(void* const* d_in, const int* in_sizes, int n_in,
                              void* d_out, int out_size, void* d_ws, size_t ws_size,
                              hipStream_t stream) {
    const float* x  = (const float*)d_in[0];
    const float* w  = (const float*)d_in[1];
    const float* b  = (const float*)d_in[2];
    float* out = (float*)d_out;

    dim3 grid(8 * 16, 4, 4);   // (n*bz, by, bx)
    dim3 block(256);
    conv_sm_pool_kernel<<<grid, block, 0, stream>>>(x, w, b, out);
}

// Round 5
// 138.496 us; speedup vs baseline: 1.8027x; 1.2263x over previous
//
#include <hip/hip_runtime.h>

#define CIN  3
#define COUT 32
// block spatial tile: 4 (z) x 16 (y) x 16 (x); each lane owns a 4-deep z-column
#define IZ 6
#define IY 18
#define IX 18
#define XT_N (CIN*IZ*IY*IX)   // 5832

// Pre-kernel: transpose weights to wT[k][c] (k = (ci*3+kd)*3*3 + kh*3 + kw)
__global__ void transpose_w_kernel(const float* __restrict__ w, float* __restrict__ wt)
{
    int i = threadIdx.x + blockIdx.x * 256;
    if (i < 81 * COUT) {
        int k = i >> 5;
        int c = i & 31;
        wt[i] = w[c * 81 + k];
    }
}

__global__ __launch_bounds__(256, 2)
void conv_sm_pool_kernel(const float* __restrict__ x,
                         const float* __restrict__ wt,   // [81][32] transposed
                         const float* __restrict__ b,
                         float* __restrict__ out)
{
    __shared__ __align__(16) float xs[XT_N];   // input halo tile only

    const int tid = threadIdx.x;
    const int nbz = blockIdx.x;      // n*16 + bz
    const int n   = nbz >> 4;
    const int bz  = nbz & 15;        // z0 = 4*bz  (also od)
    const int by  = blockIdx.y;      // y0 = 16*by
    const int bx  = blockIdx.z;      // x0 = 16*bx

    // ---- stage input halo tile (zero-padded) ----
    const int z0 = bz * 4 - 1;
    const int y0 = by * 16 - 1;
    const int x0 = bx * 16 - 1;
    for (int i = tid; i < XT_N; i += 256) {
        int t  = i;
        int xx = t % IX; t /= IX;
        int yy = t % IY; t /= IY;
        int zz = t % IZ; t /= IZ;
        int ci = t;
        int gz = z0 + zz, gy = y0 + yy, gx = x0 + xx;
        float v = 0.0f;
        if ((unsigned)gz < 64u && (unsigned)gy < 64u && (unsigned)gx < 64u)
            v = x[(((size_t)(n * CIN + ci) << 6 | gz) << 12) + (gy << 6) + gx];
        xs[i] = v;
    }
    __syncthreads();

    // ---- lane -> (py, px); each lane computes z = 4*bz + 0..3 ----
    const int lane = tid & 63;
    const int wv   = tid >> 6;            // wave 0..3 -> 8x8 (y,x) quadrant
    const int q    = lane >> 4;           // 0..3 -> 4x4 sub-quadrant (one pool output)
    const int r    = lane & 15;
    const int ry   = r >> 2;
    const int rx   = r & 3;
    const int py   = ((wv >> 1) << 3) + ((q >> 1) << 2) + ry;   // 0..15
    const int px   = ((wv & 1) << 3) + ((q & 1) << 2) + rx;     // 0..15

    // accumulators: 4 z-points x 16 channel-pairs (packed fp32)
    float2 acc2[4][16];
    {
        const float2* b2 = (const float2*)b;   // uniform loads -> SGPR
        #pragma unroll
        for (int j = 0; j < 16; ++j) {
            float2 bb = b2[j];
            #pragma unroll
            for (int p = 0; p < 4; ++p) acc2[p][j] = bb;
        }
    }

    // ---- conv: per (ci,kh): load 6x3 x-window as {v,v} pairs, 576 pk-FMAs ----
    #pragma unroll 1
    for (int ci = 0; ci < CIN; ++ci) {
        #pragma unroll 1
        for (int kh = 0; kh < 3; ++kh) {
            const int xb = ci * (IZ*IY*IX) + (py + kh) * IX + px;
            float2 x2[IZ][3];
            #pragma unroll
            for (int zz = 0; zz < IZ; ++zz)
                #pragma unroll
                for (int j = 0; j < 3; ++j) {
                    float v = xs[xb + zz * (IY*IX) + j];
                    x2[zz][j] = make_float2(v, v);
                }

            #pragma unroll
            for (int kw = 0; kw < 3; ++kw) {
                #pragma unroll
                for (int kd = 0; kd < 3; ++kd) {
                    const int k = ((ci * 3 + kd) * 3 + kh) * 3 + kw;
                    const float2* wp = (const float2*)&wt[k * COUT];  // uniform
                    #pragma unroll
                    for (int j = 0; j < 16; ++j) {
                        const float2 w2 = wp[j];   // SGPR pair (uniform)
                        #pragma unroll
                        for (int p = 0; p < 4; ++p) {
                            // acc = w2 * x2 + acc  (packed fp32, 2 ch at once)
                            asm("v_pk_fma_f32 %0, %1, %2, %0"
                                : "+v"(acc2[p][j])
                                : "s"(w2), "v"(x2[p + kd][kw]));
                        }
                    }
                }
            }
        }
    }

    // ---- softmax per point (unpack), then z-max in-lane ----
    float res[COUT];
    #pragma unroll
    for (int p = 0; p < 4; ++p) {
        float v[COUT];
        #pragma unroll
        for (int j = 0; j < 16; ++j) { v[2*j] = acc2[p][j].x; v[2*j+1] = acc2[p][j].y; }
        float m = v[0];
        #pragma unroll
        for (int c = 1; c < COUT; ++c) m = fmaxf(m, v[c]);
        float s = 0.0f;
        #pragma unroll
        for (int c = 0; c < COUT; ++c) { v[c] = __expf(v[c] - m); s += v[c]; }
        const float rs = 1.0f / s;
        #pragma unroll
        for (int c = 0; c < COUT; ++c) {
            float t = v[c] * rs;
            if (p == 0) res[c] = t; else res[c] = fmaxf(res[c], t);
        }
    }

    // ---- (y,x) 4x4 pool: butterfly max over 16-lane group ----
    #pragma unroll
    for (int c = 0; c < COUT; ++c) {
        float t = res[c];
        t = fmaxf(t, __shfl_xor(t, 1));
        t = fmaxf(t, __shfl_xor(t, 2));
        t = fmaxf(t, __shfl_xor(t, 4));
        t = fmaxf(t, __shfl_xor(t, 8));
        res[c] = t;
    }

    // ---- lane r==0 of each 16-lane group writes 32 channels ----
    if (r == 0) {
        const int od = bz;
        const int oh = 4 * by + 2 * (wv >> 1) + (q >> 1);
        const int ow = 4 * bx + 2 * (wv & 1) + (q & 1);
        size_t base = (((size_t)n * COUT) << 12) + ((size_t)od << 8) + (oh << 4) + ow;
        #pragma unroll
        for (int c = 0; c < COUT; ++c)
            out[base + ((size_t)c << 12)] = res[c];
    }
}

extern "C" void kernel_launch(void* const* d_in, const int* in_sizes, int n_in,
                              void* d_out, int out_size, void* d_ws, size_t ws_size,
                              hipStream_t stream) {
    const float* x  = (const float*)d_in[0];
    const float* w  = (const float*)d_in[1];
    const float* b  = (const float*)d_in[2];
    float* out = (float*)d_out;
    float* wt  = (float*)d_ws;   // 81*32 floats = 10368 B scratch

    transpose_w_kernel<<<11, 256, 0, stream>>>(w, wt);

    dim3 grid(8 * 16, 4, 4);   // (n*bz, by, bx)
    dim3 block(256);
    conv_sm_pool_kernel<<<grid, block, 0, stream>>>(x, wt, b, out);
}

// Round 6
// 84.754 us; speedup vs baseline: 2.9457x; 1.6341x over previous
//
#include <hip/hip_runtime.h>

typedef _Float16 half8 __attribute__((ext_vector_type(8)));
typedef float f32x16 __attribute__((ext_vector_type(16)));

#define CIN 3
#define COUT 32

// halo geometry (f16): [3 ci][6 z][18 y][34 x]
#define HZS (18*34)      // z-plane stride 612
#define HCS (6*HZS)      // ci stride 3672
#define HN  (3*HCS)      // 11016 elems, 22032 B

// K padded per-ci to 32: k = ci*32 + t, t = kd*9+kh*3+kw (0..26); t=27..31 pad.
// k=95 (s=5,hh=1,r=7) carries bias (paired with B==1.0).
// wpk layout: [s<6][hh<2][c<32][r<8] f16  (A-fragment-ready, 16B per lane)
__global__ void prep_kernel(const float* __restrict__ w,
                            const float* __restrict__ b,
                            ushort* __restrict__ wpk)
{
    int i = threadIdx.x + blockIdx.x * 256;
    if (i >= 3072) return;
    int r  = i & 7;
    int c  = (i >> 3) & 31;
    int hh = (i >> 8) & 1;
    int s  = i >> 9;
    int ci = s >> 1;
    int t  = (s & 1) * 16 + hh * 8 + r;
    float val = 0.0f;
    if (t < 27) val = w[c * 81 + ci * 27 + t];        // w[c][ci][kd][kh][kw]
    else if (s == 5 && t == 31) val = b[c];           // bias tap
    _Float16 hv = (_Float16)val;
    wpk[i] = *(ushort*)&hv;
}

__global__ __launch_bounds__(256, 3)
void conv_mfma_kernel(const float* __restrict__ x,
                      const ushort* __restrict__ wpk,
                      float* __restrict__ out)
{
    __shared__ ushort halo[HN];

    const int tid = threadIdx.x;
    const int gx0 = blockIdx.x;          // n*16 + zq
    const int n   = gx0 >> 4;
    const int zq  = gx0 & 15;            // z = zq*4 + tz
    const int yb  = blockIdx.y;          // y = yb*16 + wv*4 + ty
    const int xh  = blockIdx.z;          // x = xh*32 + (tid&31)

    // ---- stage halo (f32 -> f16) ----
    const int zg0 = zq * 4 - 1;
    const int yg0 = yb * 16 - 1;
    const int xg0 = xh * 32 - 1;
    for (int i = tid; i < HN; i += 256) {
        int t = i;
        int xx = t % 34; t /= 34;
        int yy = t % 18; t /= 18;
        int zz = t % 6;  t /= 6;
        int ci = t;
        int gz = zg0 + zz, gy = yg0 + yy, gxp = xg0 + xx;
        float v = 0.0f;
        if ((unsigned)gz < 64u && (unsigned)gy < 64u && (unsigned)gxp < 64u)
            v = x[(((size_t)(n*CIN+ci) << 6 | gz) << 12) + (gy << 6) + gxp];
        _Float16 hv = (_Float16)v;
        halo[i] = *(ushort*)&hv;
    }

    // ---- load A fragments (weights), fragment-ready layout ----
    const int hh = (tid >> 5) & 1;
    const int cc = tid & 31;
    half8 af[6];
    #pragma unroll
    for (int s = 0; s < 6; ++s)
        af[s] = *(const half8*)(wpk + ((s*2 + hh)*32 + cc)*8);

    __syncthreads();

    const int wv = tid >> 6;               // wave = y-quad within block
    const int laneBase = (wv*4)*34 + cc;   // halo elem index of (z=?,y=wv*4,x=cc)

    f32x16 res;
    #pragma unroll
    for (int j = 0; j < 16; ++j) res[j] = 0.0f;

    #pragma unroll 1
    for (int tz = 0; tz < 4; ++tz) {
      #pragma unroll 1
      for (int ty = 0; ty < 4; ++ty) {
        const int corner = laneBase + tz*HZS + ty*34;
        f32x16 acc;
        #pragma unroll
        for (int j = 0; j < 16; ++j) acc[j] = 0.0f;

        #pragma unroll
        for (int s = 0; s < 6; ++s) {
            // per-half tap-offset tables (elems), compile-time
            static constexpr int DLT0[8] = {0,1,2,34,35,36,68,69};                 // t 0..7
            static constexpr int DLT1[8] = {70,612,613,614,646,647,648,680};      // t 8..15
            static constexpr int DLT2[8] = {681,682,1224,1225,1226,1258,1259,1260};// t 16..23
            static constexpr int DLT3[3] = {1292,1293,1294};                      // t 24..26
            const int cib = (s >> 1) * HCS;
            union { ushort u[8]; half8 v; } bu;
            if (hh == 0) {
                if ((s & 1) == 0) {
                    #pragma unroll
                    for (int j = 0; j < 8; ++j) bu.u[j] = halo[corner + cib + DLT0[j]];
                } else {
                    #pragma unroll
                    for (int j = 0; j < 8; ++j) bu.u[j] = halo[corner + cib + DLT2[j]];
                }
            } else {
                if ((s & 1) == 0) {
                    #pragma unroll
                    for (int j = 0; j < 8; ++j) bu.u[j] = halo[corner + cib + DLT1[j]];
                } else {
                    #pragma unroll
                    for (int j = 0; j < 3; ++j) bu.u[j] = halo[corner + cib + DLT3[j]];
                    bu.u[3] = 0; bu.u[4] = 0; bu.u[5] = 0; bu.u[6] = 0;
                    bu.u[7] = (s == 5) ? (ushort)0x3C00 : (ushort)0;  // bias partner 1.0
                }
            }
            acc = __builtin_amdgcn_mfma_f32_32x32x16_f16(af[s], bu.v, acc, 0, 0, 0);
        }

        // softmax over 32 channels: 16 in-lane + partner lane (l^32)
        float mx = acc[0];
        #pragma unroll
        for (int j = 1; j < 16; ++j) mx = fmaxf(mx, acc[j]);
        mx = fmaxf(mx, __shfl_xor(mx, 32));
        float sum = 0.0f;
        #pragma unroll
        for (int j = 0; j < 16; ++j) { float e = __expf(acc[j] - mx); acc[j] = e; sum += e; }
        sum += __shfl_xor(sum, 32);
        const float inv = 1.0f / sum;
        // z,y-pool: in-lane running max across the 16 (tz,ty) tiles
        #pragma unroll
        for (int j = 0; j < 16; ++j) res[j] = fmaxf(res[j], acc[j] * inv);
      }
    }

    // x-pool over lane quads (x = xh*32 + cc)
    #pragma unroll
    for (int j = 0; j < 16; ++j) {
        float v = res[j];
        v = fmaxf(v, __shfl_xor(v, 1));
        v = fmaxf(v, __shfl_xor(v, 2));
        res[j] = v;
    }

    if ((tid & 3) == 0) {
        const int xqg = xh*8 + (cc >> 2);
        const int yqg = yb*4 + wv;
        #pragma unroll
        for (int j = 0; j < 16; ++j) {
            int c = (j & 3) + 8*(j >> 2) + 4*hh;   // C/D row mapping
            out[(((size_t)(n*COUT + c)*16 + zq)*16 + yqg)*16 + xqg] = res[j];
        }
    }
}

extern "C" void kernel_launch(void* const* d_in, const int* in_sizes, int n_in,
                              void* d_out, int out_size, void* d_ws, size_t ws_size,
                              hipStream_t stream) {
    const float* x  = (const float*)d_in[0];
    const float* w  = (const float*)d_in[1];
    const float* b  = (const float*)d_in[2];
    float* out = (float*)d_out;
    ushort* wpk = (ushort*)d_ws;   // 3072 f16 = 6144 B scratch

    prep_kernel<<<12, 256, 0, stream>>>(w, b, wpk);

    dim3 grid(8 * 16, 4, 2);   // (n*zq, yb, xh)
    conv_mfma_kernel<<<grid, 256, 0, stream>>>(x, wpk, out);
}

// Round 7
// 55.742 us; speedup vs baseline: 4.4789x; 1.5205x over previous
//
#include <hip/hip_runtime.h>

typedef _Float16 half8 __attribute__((ext_vector_type(8)));
typedef float f32x16 __attribute__((ext_vector_type(16)));

#define CIN 3
#define COUT 32
// halo (f16): [3 ci][6 z][18 y][36 x]
#define IXH 36
#define HZS (18*IXH)      // 648 elems
#define HCS (6*HZS)       // 3888
#define HN  (3*HCS)       // 11664 elems = 23328 B
// u32-unit strides
#define HY4  (IXH/2)      // 18
#define HZS4 (HZS/2)      // 324
#define HCS4 (HCS/2)      // 1944

// K order per ci (32 slots): pi: tt<8 -> t=tt ; 8..15 -> t=tt+8 ; 16..23 -> t=tt-8 ;
// 24..31 -> t=tt (24..26 real, 31@s5 = bias). t = kd*9+kh*3+kw.
// wpk layout: [s<6][hh<2][c<32][r<8] f16
__global__ void prep_kernel(const float* __restrict__ w,
                            const float* __restrict__ b,
                            ushort* __restrict__ wpk)
{
    int i = threadIdx.x + blockIdx.x * 256;
    if (i >= 3072) return;
    int r  = i & 7;
    int c  = (i >> 3) & 31;
    int hh = (i >> 8) & 1;
    int s  = i >> 9;
    int ci = s >> 1;
    int tt = (s & 1) * 16 + hh * 8 + r;
    int t;
    if (tt < 8)       t = tt;
    else if (tt < 16) t = tt + 8;
    else if (tt < 24) t = tt - 8;
    else              t = tt;
    float val = 0.0f;
    if (t < 27) val = w[c * 81 + ci * 27 + t];
    else if (s == 5 && tt == 31) val = b[c];
    _Float16 hv = (_Float16)val;
    wpk[i] = *(ushort*)&hv;
}

__global__ __launch_bounds__(256, 3)
void conv_mfma_kernel(const float* __restrict__ x,
                      const ushort* __restrict__ wpk,
                      float* __restrict__ out)
{
    __shared__ ushort halo[HN];

    const int tid = threadIdx.x;
    const int gx0 = blockIdx.x;          // n*16 + zq
    const int n   = gx0 >> 4;
    const int zq  = gx0 & 15;
    const int yb  = blockIdx.y;
    const int xh  = blockIdx.z;

    // ---- stage halo (f32 pairs -> packed f16) ----
    const int zg0 = zq * 4 - 1;
    const int yg0 = yb * 16 - 1;
    const int xg0 = xh * 32 - 2;
    uint* h32w = (uint*)halo;
    for (int m = tid; m < HN/2; m += 256) {
        int t = m;
        int xp = t % 18; t /= 18;        // x-pair index
        int yy = t % 18; t /= 18;
        int zz = t % 6;
        int ci = t / 6;
        int gz = zg0 + zz, gy = yg0 + yy, gxp = xg0 + 2*xp;
        uint pk = 0;
        if ((unsigned)gz < 64u && (unsigned)gy < 64u && (unsigned)gxp < 64u) {
            const float* p = &x[(((size_t)(n*CIN+ci) << 6 | gz) << 12) + (gy << 6) + gxp];
            float2 f = *(const float2*)p;
            _Float16 h0 = (_Float16)f.x, h1 = (_Float16)f.y;
            pk = (uint)*(ushort*)&h0 | ((uint)*(ushort*)&h1 << 16);
        }
        h32w[m] = pk;
    }

    // ---- A fragments ----
    const int hh = (tid >> 5) & 1;
    const int cc = tid & 31;
    half8 af[6];
    #pragma unroll
    for (int s = 0; s < 6; ++s)
        af[s] = *(const half8*)(wpk + ((s*2 + hh)*32 + cc)*8);

    __syncthreads();

    const int wv = tid >> 6;             // y-quad
    const uint* h32 = (const uint*)halo;
    const uint shamt = ((cc + 1) & 1) * 16;                 // normalize odd-x
    const int  cb4   = ((cc + 1) >> 1) + (wv*4)*HY4 + hh*HZS4;

    f32x16 res;
    #pragma unroll
    for (int j = 0; j < 16; ++j) res[j] = 0.0f;

    #pragma unroll 1
    for (int tz = 0; tz < 4; ++tz) {
      #pragma unroll 1
      for (int tyh = 0; tyh < 2; ++tyh) {
        const int sb4 = cb4 + tz*HZS4 + tyh*(2*HY4);
        // load 24 rows (2 planes x 4 y x 3 ci), normalized
        uint2 rw[3][2][4];
        #pragma unroll
        for (int ci = 0; ci < 3; ++ci)
          #pragma unroll
          for (int p = 0; p < 2; ++p) {
            const uint* bp = h32 + sb4 + ci*HCS4 + p*HZS4;
            #pragma unroll
            for (int yy = 0; yy < 4; ++yy) {
                uint lo = bp[yy*HY4];
                uint hi = bp[yy*HY4 + 1];
                unsigned long long v = (((unsigned long long)hi) << 32) | lo;
                v >>= shamt;
                rw[ci][p][yy] = make_uint2((uint)v, (uint)(v >> 32));
            }
          }

        #pragma unroll
        for (int tyl = 0; tyl < 2; ++tyl) {
            f32x16 acc;
            #pragma unroll
            for (int j = 0; j < 16; ++j) acc[j] = 0.0f;

            #pragma unroll
            for (int ci = 0; ci < 3; ++ci) {
                uint2 a0 = rw[ci][0][tyl+0], a1 = rw[ci][0][tyl+1], a2 = rw[ci][0][tyl+2];
                uint2 b0 = rw[ci][1][tyl+0], b1 = rw[ci][1][tyl+1], b2 = rw[ci][1][tyl+2];
                uint fe0, fe1, fe2, fe3, fo0, fo1, fo2, fo3;
                if (hh == 0) {
                    fe0 = a0.x;
                    fe1 = (a0.y & 0xffffu) | (a1.x << 16);
                    fe2 = (a1.x >> 16) | (a1.y << 16);
                    fe3 = a2.x;
                    fo0 = (a2.y & 0xffffu) | (b0.x << 16);
                    fo1 = (b0.x >> 16) | (b0.y << 16);
                    fo2 = b1.x;
                    fo3 = (b1.y & 0xffffu) | (b2.x << 16);
                } else {
                    fe0 = (a2.x >> 16) | (a2.y << 16);
                    fe1 = b0.x;
                    fe2 = (b0.y & 0xffffu) | (b1.x << 16);
                    fe3 = (b1.x >> 16) | (b1.y << 16);
                    fo0 = b2.x;
                    fo1 = b2.y & 0xffffu;
                    fo2 = 0u;
                    fo3 = (ci == 2) ? 0x3C000000u : 0u;   // bias partner 1.0
                }
                union { uint u[4]; half8 h; } ue, uo;
                ue.u[0] = fe0; ue.u[1] = fe1; ue.u[2] = fe2; ue.u[3] = fe3;
                uo.u[0] = fo0; uo.u[1] = fo1; uo.u[2] = fo2; uo.u[3] = fo3;
                acc = __builtin_amdgcn_mfma_f32_32x32x16_f16(af[ci*2    ], ue.h, acc, 0, 0, 0);
                acc = __builtin_amdgcn_mfma_f32_32x32x16_f16(af[ci*2 + 1], uo.h, acc, 0, 0, 0);
            }

            // softmax over 32 ch: 16 in-lane + partner (l^32)
            float mx = acc[0];
            #pragma unroll
            for (int j = 1; j < 16; ++j) mx = fmaxf(mx, acc[j]);
            mx = fmaxf(mx, __shfl_xor(mx, 32));
            float sum = 0.0f;
            #pragma unroll
            for (int j = 0; j < 16; ++j) { float e = __expf(acc[j] - mx); acc[j] = e; sum += e; }
            sum += __shfl_xor(sum, 32);
            const float inv = 1.0f / sum;
            #pragma unroll
            for (int j = 0; j < 16; ++j) res[j] = fmaxf(res[j], acc[j] * inv);
        }
      }
    }

    // x-pool over lane quads
    #pragma unroll
    for (int j = 0; j < 16; ++j) {
        float v = res[j];
        v = fmaxf(v, __shfl_xor(v, 1));
        v = fmaxf(v, __shfl_xor(v, 2));
        res[j] = v;
    }

    if ((tid & 3) == 0) {
        const int xqg = xh*8 + (cc >> 2);
        const int yqg = yb*4 + wv;
        #pragma unroll
        for (int j = 0; j < 16; ++j) {
            int c = (j & 3) + 8*(j >> 2) + 4*hh;
            out[(((size_t)(n*COUT + c)*16 + zq)*16 + yqg)*16 + xqg] = res[j];
        }
    }
}

extern "C" void kernel_launch(void* const* d_in, const int* in_sizes, int n_in,
                              void* d_out, int out_size, void* d_ws, size_t ws_size,
                              hipStream_t stream) {
    const float* x  = (const float*)d_in[0];
    const float* w  = (const float*)d_in[1];
    const float* b  = (const float*)d_in[2];
    float* out = (float*)d_out;
    ushort* wpk = (ushort*)d_ws;   // 3072 f16 = 6144 B scratch

    prep_kernel<<<12, 256, 0, stream>>>(w, b, wpk);

    dim3 grid(8 * 16, 4, 2);   // (n*zq, yb, xh)
    conv_mfma_kernel<<<grid, 256, 0, stream>>>(x, wpk, out);
}

// Round 9
// 50.904 us; speedup vs baseline: 4.9045x; 1.0950x over previous
//
#include <hip/hip_runtime.h>

typedef _Float16 half8 __attribute__((ext_vector_type(8)));
typedef float f32x16 __attribute__((ext_vector_type(16)));

#define CIN 3
#define COUT 32
// halo (f16): [3 ci][6 z][18 y][36 x]
#define IXH 36
#define HZS (18*IXH)      // 648 elems
#define HCS (6*HZS)       // 3888
#define HN  (3*HCS)       // 11664 elems = 23328 B
// u32-unit strides
#define HY4  (IXH/2)      // 18
#define HZS4 (HZS/2)      // 324
#define HCS4 (HCS/2)      // 1944

#define LOG2E 1.4426950408889634f

// K order per ci (32 slots): pi: tt<8 -> t=tt ; 8..15 -> t=tt+8 ; 16..23 -> t=tt-8 ;
// 24..31 -> t=tt (24..26 real, 31@s5 = bias). t = kd*9+kh*3+kw.
// wpk layout: [s<6][hh<2][c<32][r<8] f16.  Weights/bias pre-scaled by log2(e)
// so the softmax exp becomes a bare v_exp_f32 (2^x).
__global__ void prep_kernel(const float* __restrict__ w,
                            const float* __restrict__ b,
                            ushort* __restrict__ wpk)
{
    int i = threadIdx.x + blockIdx.x * 256;
    if (i >= 3072) return;
    int r  = i & 7;
    int c  = (i >> 3) & 31;
    int hh = (i >> 8) & 1;
    int s  = i >> 9;
    int ci = s >> 1;
    int tt = (s & 1) * 16 + hh * 8 + r;
    int t;
    if (tt < 8)       t = tt;
    else if (tt < 16) t = tt + 8;
    else if (tt < 24) t = tt - 8;
    else              t = tt;
    float val = 0.0f;
    if (t < 27) val = w[c * 81 + ci * 27 + t] * LOG2E;
    else if (s == 5 && tt == 31) val = b[c] * LOG2E;
    _Float16 hv = (_Float16)val;
    wpk[i] = *(ushort*)&hv;
}

__global__ __launch_bounds__(256, 4)
void conv_mfma_kernel(const float* __restrict__ x,
                      const ushort* __restrict__ wpk,
                      float* __restrict__ out)
{
    __shared__ ushort halo[HN];

    const int tid = threadIdx.x;
    const int gx0 = blockIdx.x;          // n*16 + zq
    const int n   = gx0 >> 4;
    const int zq  = gx0 & 15;
    const int yb  = blockIdx.y;
    const int xh  = blockIdx.z;

    // ---- stage halo (f32 pairs -> packed f16), plane-structured ----
    const int zg0 = zq * 4 - 1;
    const int yg0 = yb * 16 - 1;
    const int xg0 = xh * 32 - 2;
    uint* h32w = (uint*)halo;
    {
        const int q0 = tid;              // chunk 0 within a 324-u32 plane
        const int q1 = tid + 256;        // chunk 1 (valid for tid<68)
        const int xp0 = q0 % 18, yy0 = q0 / 18;
        const int xp1 = q1 % 18, yy1 = q1 / 18;
        const int gy0 = yg0 + yy0, gxp0 = xg0 + 2*xp0;
        const int gy1 = yg0 + yy1, gxp1 = xg0 + 2*xp1;
        const bool v0 = ((unsigned)gy0 < 64u) & ((unsigned)gxp0 < 64u);
        const bool v1 = (tid < 68) && (((unsigned)gy1 < 64u) & ((unsigned)gxp1 < 64u));
        #pragma unroll 1
        for (int pl = 0; pl < 18; ++pl) {
            const int ci = (unsigned)pl / 6u;
            const int zz = pl - ci * 6;
            const int gz = zg0 + zz;
            const bool zv = (unsigned)gz < 64u;
            uint pk0 = 0, pk1 = 0;
            if (zv & v0) {
                const float* p = &x[(((size_t)(n*CIN+ci) << 6 | gz) << 12) + (gy0 << 6) + gxp0];
                float2 f = *(const float2*)p;
                _Float16 h0 = (_Float16)f.x, h1 = (_Float16)f.y;
                pk0 = (uint)*(ushort*)&h0 | ((uint)*(ushort*)&h1 << 16);
            }
            h32w[pl*HZS4 + q0] = pk0;
            if (tid < 68) {
                if (zv & v1) {
                    const float* p = &x[(((size_t)(n*CIN+ci) << 6 | gz) << 12) + (gy1 << 6) + gxp1];
                    float2 f = *(const float2*)p;
                    _Float16 h0 = (_Float16)f.x, h1 = (_Float16)f.y;
                    pk1 = (uint)*(ushort*)&h0 | ((uint)*(ushort*)&h1 << 16);
                }
                h32w[pl*HZS4 + q1] = pk1;
            }
        }
    }

    // ---- A fragments ----
    const int hh = (tid >> 5) & 1;
    const int cc = tid & 31;
    half8 af[6];
    #pragma unroll
    for (int s = 0; s < 6; ++s)
        af[s] = *(const half8*)(wpk + ((s*2 + hh)*32 + cc)*8);

    __syncthreads();

    const int wv = tid >> 6;             // y-quad
    const uint* h32 = (const uint*)halo;
    const uint shamt = ((cc + 1) & 1) * 16;                 // normalize odd-x
    const int  cb4   = ((cc + 1) >> 1) + (wv*4)*HY4 + hh*HZS4;

    f32x16 res;
    #pragma unroll
    for (int j = 0; j < 16; ++j) res[j] = 0.0f;

    #pragma unroll 1
    for (int tz = 0; tz < 4; ++tz) {
      #pragma unroll 1
      for (int tyh = 0; tyh < 2; ++tyh) {
        const int sb4 = cb4 + tz*HZS4 + tyh*(2*HY4);
        // load 24 rows (2 planes x 4 y x 3 ci), normalized
        uint2 rw[3][2][4];
        #pragma unroll
        for (int ci = 0; ci < 3; ++ci)
          #pragma unroll
          for (int p = 0; p < 2; ++p) {
            const uint* bp = h32 + sb4 + ci*HCS4 + p*HZS4;
            #pragma unroll
            for (int yy = 0; yy < 4; ++yy) {
                uint lo = bp[yy*HY4];
                uint hi = bp[yy*HY4 + 1];
                unsigned long long v = (((unsigned long long)hi) << 32) | lo;
                v >>= shamt;
                rw[ci][p][yy] = make_uint2((uint)v, (uint)(v >> 32));
            }
          }

        #pragma unroll
        for (int tyl = 0; tyl < 2; ++tyl) {
            f32x16 acc;
            #pragma unroll
            for (int j = 0; j < 16; ++j) acc[j] = 0.0f;

            #pragma unroll
            for (int ci = 0; ci < 3; ++ci) {
                uint2 a0 = rw[ci][0][tyl+0], a1 = rw[ci][0][tyl+1], a2 = rw[ci][0][tyl+2];
                uint2 b0 = rw[ci][1][tyl+0], b1 = rw[ci][1][tyl+1], b2 = rw[ci][1][tyl+2];
                uint fe0, fe1, fe2, fe3, fo0, fo1, fo2, fo3;
                if (hh == 0) {
                    fe0 = a0.x;
                    fe1 = (a0.y & 0xffffu) | (a1.x << 16);
                    fe2 = (a1.x >> 16) | (a1.y << 16);
                    fe3 = a2.x;
                    fo0 = (a2.y & 0xffffu) | (b0.x << 16);
                    fo1 = (b0.x >> 16) | (b0.y << 16);
                    fo2 = b1.x;
                    fo3 = (b1.y & 0xffffu) | (b2.x << 16);
                } else {
                    fe0 = (a2.x >> 16) | (a2.y << 16);
                    fe1 = b0.x;
                    fe2 = (b0.y & 0xffffu) | (b1.x << 16);
                    fe3 = (b1.x >> 16) | (b1.y << 16);
                    fo0 = b2.x;
                    fo1 = b2.y & 0xffffu;
                    fo2 = 0u;
                    fo3 = (ci == 2) ? 0x3C000000u : 0u;   // bias partner 1.0
                }
                union { uint u[4]; half8 h; } ue, uo;
                ue.u[0] = fe0; ue.u[1] = fe1; ue.u[2] = fe2; ue.u[3] = fe3;
                uo.u[0] = fo0; uo.u[1] = fo1; uo.u[2] = fo2; uo.u[3] = fo3;
                acc = __builtin_amdgcn_mfma_f32_32x32x16_f16(af[ci*2    ], ue.h, acc, 0, 0, 0);
                acc = __builtin_amdgcn_mfma_f32_32x32x16_f16(af[ci*2 + 1], uo.h, acc, 0, 0, 0);
            }

            // softmax over 32 ch (no max-sub; weights pre-scaled by log2e):
            // e = 2^acc ; sum in-lane tree + partner (l^32) ; rcp ; pool-max
            float e[16];
            #pragma unroll
            for (int j = 0; j < 16; ++j) e[j] = __builtin_amdgcn_exp2f(acc[j]);
            float s0 = (e[0]+e[1]) + (e[2]+e[3]);
            float s1 = (e[4]+e[5]) + (e[6]+e[7]);
            float s2 = (e[8]+e[9]) + (e[10]+e[11]);
            float s3 = (e[12]+e[13]) + (e[14]+e[15]);
            float sum = (s0+s1) + (s2+s3);
            sum += __shfl_xor(sum, 32);
            const float inv = __builtin_amdgcn_rcpf(sum);
            #pragma unroll
            for (int j = 0; j < 16; ++j) res[j] = fmaxf(res[j], e[j] * inv);
        }
      }
    }

    // x-pool over lane quads
    #pragma unroll
    for (int j = 0; j < 16; ++j) {
        float v = res[j];
        v = fmaxf(v, __shfl_xor(v, 1));
        v = fmaxf(v, __shfl_xor(v, 2));
        res[j] = v;
    }

    if ((tid & 3) == 0) {
        const int xqg = xh*8 + (cc >> 2);
        const int yqg = yb*4 + wv;
        #pragma unroll
        for (int j = 0; j < 16; ++j) {
            int c = (j & 3) + 8*(j >> 2) + 4*hh;
            out[(((size_t)(n*COUT + c)*16 + zq)*16 + yqg)*16 + xqg] = res[j];
        }
    }
}

extern "C" void kernel_launch(void* const* d_in, const int* in_sizes, int n_in,
                              void* d_out, int out_size, void* d_ws, size_t ws_size,
                              hipStream_t stream) {
    const float* x  = (const float*)d_in[0];
    const float* w  = (const float*)d_in[1];
    const float* b  = (const float*)d_in[2];
    float* out = (float*)d_out;
    ushort* wpk = (ushort*)d_ws;   // 3072 f16 = 6144 B scratch

    prep_kernel<<<12, 256, 0, stream>>>(w, b, wpk);

    dim3 grid(8 * 16, 4, 2);   // (n*zq, yb, xh)
    conv_mfma_kernel<<<grid, 256, 0, stream>>>(x, wpk, out);
}